// Round 6
// baseline (276.469 us; speedup 1.0000x reference)
//
#include <hip/hip_runtime.h>

// Problem constants
constexpr int Bc = 2, Sc = 2048, Dc = 256, Hc = 8, DKc = 32;
constexpr int BH = Bc * Hc;

typedef _Float16 f16x8 __attribute__((ext_vector_type(8)));
typedef _Float16 f16x4 __attribute__((ext_vector_type(4)));
typedef float    f32x4 __attribute__((ext_vector_type(4)));

// ---------------------------------------------------------------------------
// K1: three projections in one launch (z = 0:Q, 1:K^T, 2:V^T)
// out = scale * (X @ W); vtrans=0: [b][h][s][dk], vtrans=1: [b][h][dk][s]
// ---------------------------------------------------------------------------
__global__ __launch_bounds__(256) void proj3_kernel(
    const float* __restrict__ query, const float* __restrict__ key_,
    const float* __restrict__ value, const float* __restrict__ Wq,
    const float* __restrict__ Wk, const float* __restrict__ Wv,
    _Float16* __restrict__ Qb, _Float16* __restrict__ Kt,
    _Float16* __restrict__ Vt)
{
    constexpr int ROWS = 8;
    __shared__ float xs[ROWS][Dc];
    const int z = blockIdx.y;
    const float* X = (z == 0) ? query : (z == 1) ? key_ : value;
    const float* W = (z == 0) ? Wq : (z == 1) ? Wk : Wv;
    _Float16* out = (z == 0) ? Qb : (z == 1) ? Kt : Vt;
    const int vtrans = (z != 0);
    const float scale = (z == 0) ? 0.17677669529663689f : 1.0f;

    const int r0 = blockIdx.x * ROWS;       // global row = b*S + s
    const int t = threadIdx.x;
    #pragma unroll
    for (int i = 0; i < ROWS; ++i)
        xs[i][t] = X[(long)(r0 + i) * Dc + t];
    __syncthreads();
    float acc[ROWS];
    #pragma unroll
    for (int i = 0; i < ROWS; ++i) acc[i] = 0.f;
    for (int d = 0; d < Dc; ++d) {
        float w = W[d * Dc + t];
        #pragma unroll
        for (int i = 0; i < ROWS; ++i) acc[i] = fmaf(xs[i][d], w, acc[i]);
    }
    const int h = t >> 5, dk = t & 31;
    #pragma unroll
    for (int i = 0; i < ROWS; ++i) {
        int row = r0 + i;
        int b = row / Sc, s = row % Sc;
        long idx = vtrans ? (((long)(b * Hc + h) * DKc + dk) * Sc + s)
                          : (((long)(b * Hc + h) * Sc + s) * DKc + dk);
        out[idx] = (_Float16)(acc[i] * scale);
    }
}

// ---------------------------------------------------------------------------
// K1b: relT[b][n][k] = relation[b][k][n]  (f32 -> f16, 64x64 LDS transpose)
// ---------------------------------------------------------------------------
__global__ __launch_bounds__(256) void relT_kernel(
    const float* __restrict__ rel, _Float16* __restrict__ relT)
{
    __shared__ float tile[64][65];
    const int b = blockIdx.z;
    const int k0 = blockIdx.y * 64, n0 = blockIdx.x * 64;
    const int tx = threadIdx.x & 63, ty = threadIdx.x >> 6;
    const float* src = rel + (long)b * Sc * Sc;
    #pragma unroll
    for (int i = 0; i < 16; ++i) {
        int k = i * 4 + ty;
        tile[k][tx] = src[(long)(k0 + k) * Sc + n0 + tx];
    }
    __syncthreads();
    _Float16* dst = relT + (long)b * Sc * Sc;
    #pragma unroll
    for (int i = 0; i < 16; ++i) {
        int n = i * 4 + ty;
        dst[(long)(n0 + n) * Sc + k0 + tx] = (_Float16)tile[tx][n];
    }
}

// ---------------------------------------------------------------------------
// K1c: pack mask bytes (0/1) into bits.
// ---------------------------------------------------------------------------
__global__ __launch_bounds__(256) void maskpack_kernel(
    const unsigned int* __restrict__ m, unsigned int* __restrict__ out)
{
    const int idx = blockIdx.x * 256 + threadIdx.x;   // one output uint
    const uint4 a = ((const uint4*)m)[idx * 2];
    const uint4 b = ((const uint4*)m)[idx * 2 + 1];
    unsigned int ws[8] = {a.x, a.y, a.z, a.w, b.x, b.y, b.z, b.w};
    unsigned int r = 0;
    #pragma unroll
    for (int j = 0; j < 8; ++j) {
        unsigned int nib = (ws[j] | (ws[j] >> 7) | (ws[j] >> 14) | (ws[j] >> 21)) & 0xFu;
        r |= nib << (4 * j);
    }
    out[idx] = r;
}

// ---------------------------------------------------------------------------
// K2: KR GEMM.  KRT[b][n][hd] = sum_k relT[b][n][k] * Kt[b][hd][k]
// BM=BN=64, BK=64, 4 waves (2x2) each 32x32 quadrant -> 256 blocks.
// ---------------------------------------------------------------------------
__global__ __launch_bounds__(256) void kr_kernel(
    const _Float16* __restrict__ relT, const _Float16* __restrict__ Kt,
    _Float16* __restrict__ KRT)
{
    constexpr int LDK = 72;
    __shared__ _Float16 As[64][LDK];
    __shared__ _Float16 Bs[64][LDK];
    const int b = blockIdx.z;
    const int m0 = blockIdx.y * 64;      // n (rel col) tile
    const int n0 = blockIdx.x * 64;      // hd tile
    const _Float16* Ap = relT + (long)b * Sc * Sc;
    const _Float16* Bp = Kt + (long)b * Hc * DKc * Sc;
    const int t = threadIdx.x;
    const int lane = t & 63, wave = t >> 6;
    const int wr = wave >> 1, wc = wave & 1;
    const int c = lane & 15, g = lane >> 4;
    const int lrow = t >> 2;             // 0..63
    const int lcol = (t & 3) * 16;       // 0,16,32,48
    f32x4 acc[2][2] = {};
    for (int k0 = 0; k0 < Sc; k0 += 64) {
        *(f16x8*)&As[lrow][lcol]     = *(const f16x8*)&Ap[(long)(m0 + lrow) * Sc + k0 + lcol];
        *(f16x8*)&As[lrow][lcol + 8] = *(const f16x8*)&Ap[(long)(m0 + lrow) * Sc + k0 + lcol + 8];
        *(f16x8*)&Bs[lrow][lcol]     = *(const f16x8*)&Bp[(long)(n0 + lrow) * Sc + k0 + lcol];
        *(f16x8*)&Bs[lrow][lcol + 8] = *(const f16x8*)&Bp[(long)(n0 + lrow) * Sc + k0 + lcol + 8];
        __syncthreads();
        #pragma unroll
        for (int kk = 0; kk < 2; ++kk) {
            const int kb = kk * 32 + g * 8;
            f16x8 af[2], bf[2];
            #pragma unroll
            for (int m = 0; m < 2; ++m)
                af[m] = *(const f16x8*)&As[wr * 32 + m * 16 + c][kb];
            #pragma unroll
            for (int n = 0; n < 2; ++n)
                bf[n] = *(const f16x8*)&Bs[wc * 32 + n * 16 + c][kb];
            #pragma unroll
            for (int m = 0; m < 2; ++m)
                #pragma unroll
                for (int n = 0; n < 2; ++n)
                    acc[m][n] = __builtin_amdgcn_mfma_f32_16x16x32_f16(
                        af[m], bf[n], acc[m][n], 0, 0, 0);
        }
        __syncthreads();
    }
    _Float16* outp = KRT + (long)b * Sc * 256;
    #pragma unroll
    for (int m = 0; m < 2; ++m)
        #pragma unroll
        for (int n = 0; n < 2; ++n)
            #pragma unroll
            for (int i = 0; i < 4; ++i) {
                int row = m0 + wr * 32 + m * 16 + g * 4 + i;
                int col = n0 + wc * 32 + n * 16 + c;
                outp[(long)row * 256 + col] = (_Float16)acc[m][n][i];
            }
}

// ---------------------------------------------------------------------------
// K3: fused attention, SINGLE compute pass.
// s = mfma(KR, Q) once; p16 = exp(s) kept in 64 VGPRs (all indices static);
// esum in f32; PV on UNNORMALIZED p (scaled by shfl'd rinv at end).
// Store pass: replay p_regs -> p_lds -> rinv-scale -> 512B-contiguous
// nontemporal f32 stores.  No __syncthreads (LDS wave-private).
// ---------------------------------------------------------------------------
__global__ __launch_bounds__(256) void fused_attn_kernel(
    const _Float16* __restrict__ Qb,   // [BH][S][32], pre-scaled 1/sqrt(32)
    const _Float16* __restrict__ KRT,  // [B][S][256]
    const _Float16* __restrict__ Vt,   // [BH][32][S]
    const unsigned int* __restrict__ mbits, // [B][S][S/32]
    float* __restrict__ attn_out,      // [BH][S][S]
    float* __restrict__ attw)          // [B*S][256]
{
    constexpr int NT = 128, NTILES = Sc / NT, LDP = 136;
    __shared__ _Float16 p_lds[64][LDP];
    const int bh = blockIdx.y;
    const int b = bh >> 3, h = bh & 7;
    const int q0 = blockIdx.x * 64;
    const int t = threadIdx.x, lane = t & 63, w = t >> 6;
    const int c = lane & 15, g = lane >> 4;
    const int q = q0 + w * 16 + c;           // this lane's q row
    const f16x8 qf = *(const f16x8*)&Qb[((long)bh * Sc + q) * DKc + g * 8];
    const _Float16* krt = KRT + (long)b * Sc * 256 + h * 32;
    const unsigned int* mbitrow = mbits + ((long)b * Sc + q) * (Sc / 32);
    const f32x4 zero = {};

    f16x4 p_regs[NTILES][8];                 // 64 VGPRs, static indices only
    f32x4 acc[2] = {};
    float esum = 0.f;

    // ---- single compute pass: s -> mask -> exp -> {p_regs, esum, PV} ----
    #pragma unroll
    for (int nt = 0; nt < NTILES; ++nt) {
        const int n0 = nt * NT;
        f32x4 s[8];
        #pragma unroll
        for (int nf = 0; nf < 8; ++nf) {
            f16x8 kf = *(const f16x8*)&krt[(long)(n0 + nf * 16 + c) * 256 + g * 8];
            s[nf] = __builtin_amdgcn_mfma_f32_16x16x32_f16(kf, qf, zero, 0, 0, 0);
        }
        const uint4 mq = *(const uint4*)&mbitrow[nt * 4];
        const unsigned int mwv[4] = {mq.x, mq.y, mq.z, mq.w};
        #pragma unroll
        for (int nf = 0; nf < 8; ++nf) {
            const unsigned int bits = mwv[nf >> 1] >> ((nf & 1) * 16 + g * 4);
            f16x4 pv;
            #pragma unroll
            for (int i = 0; i < 4; ++i) {
                float sv = ((bits >> i) & 1u) ? -1e9f : s[nf][i];
                float p = __expf(sv);
                esum += p;
                pv[i] = (_Float16)p;
            }
            p_regs[nt][nf] = pv;
            *(f16x4*)&p_lds[w * 16 + c][nf * 16 + g * 4] = pv;
        }
        #pragma unroll
        for (int ks = 0; ks < 4; ++ks) {
            f16x8 af = *(const f16x8*)&p_lds[w * 16 + c][ks * 32 + g * 8];
            #pragma unroll
            for (int nb = 0; nb < 2; ++nb) {
                f16x8 vf = *(const f16x8*)&Vt[((long)bh * DKc + nb * 16 + c) * Sc + n0 + ks * 32 + g * 8];
                acc[nb] = __builtin_amdgcn_mfma_f32_16x16x32_f16(af, vf, acc[nb], 0, 0, 0);
            }
        }
    }
    esum += __shfl_xor(esum, 16);
    esum += __shfl_xor(esum, 32);
    const float rinv = 1.f / esum;           // uniform over g; per-row at lane c

    // ---- store pass: replay p_regs, scale, contiguous stores ----
    float* aoutw = attn_out + (long)bh * Sc * Sc
                 + (long)(q0 + w * 16 + (lane >> 5)) * Sc + (lane & 31) * 4;
    #pragma unroll
    for (int nt = 0; nt < NTILES; ++nt) {
        #pragma unroll
        for (int nf = 0; nf < 8; ++nf)
            *(f16x4*)&p_lds[w * 16 + c][nf * 16 + g * 4] = p_regs[nt][nf];
        #pragma unroll
        for (int r2 = 0; r2 < 8; ++r2) {
            const int lrow = r2 * 2 + (lane >> 5);
            f16x4 pv = *(const f16x4*)&p_lds[w * 16 + lrow][(lane & 31) * 4];
            const float rs = __shfl(rinv, lrow);
            f32x4 av;
            #pragma unroll
            for (int i = 0; i < 4; ++i) av[i] = (float)pv[i] * rs;
            __builtin_nontemporal_store(av, (f32x4*)&aoutw[(long)(r2 * 2) * Sc + nt * NT]);
        }
    }
    #pragma unroll
    for (int nb = 0; nb < 2; ++nb)
        #pragma unroll
        for (int i = 0; i < 4; ++i) {
            const float rs = __shfl(rinv, g * 4 + i);
            attw[((long)(b * Sc + q0 + w * 16 + g * 4 + i)) * Dc + h * 32 + nb * 16 + c]
                = acc[nb][i] * rs;
        }
}

// ---------------------------------------------------------------------------
// K4: out = LayerNorm(att @ Wfc + bfc + query) * gamma + beta
// ---------------------------------------------------------------------------
__global__ __launch_bounds__(256) void out_kernel(
    const float* __restrict__ att, const float* __restrict__ Wfc,
    const float* __restrict__ bfc, const float* __restrict__ query,
    const float* __restrict__ gamma, const float* __restrict__ beta,
    float* __restrict__ out)
{
    __shared__ float xs[4][Dc];
    __shared__ float ys[4][Dc];
    const int r0 = blockIdx.x * 4;
    const int t = threadIdx.x;
    #pragma unroll
    for (int i = 0; i < 4; ++i) xs[i][t] = att[(long)(r0 + i) * Dc + t];
    __syncthreads();
    float acc[4] = {0.f, 0.f, 0.f, 0.f};
    for (int d = 0; d < Dc; ++d) {
        float wv = Wfc[d * Dc + t];
        #pragma unroll
        for (int i = 0; i < 4; ++i) acc[i] = fmaf(xs[i][d], wv, acc[i]);
    }
    const float bias = bfc[t];
    #pragma unroll
    for (int i = 0; i < 4; ++i)
        ys[i][t] = acc[i] + bias + query[(long)(r0 + i) * Dc + t];
    __syncthreads();
    const int w = t >> 6, lane = t & 63;
    float x0 = ys[w][lane], x1 = ys[w][lane + 64];
    float x2 = ys[w][lane + 128], x3 = ys[w][lane + 192];
    float sum = x0 + x1 + x2 + x3;
    float sq = x0 * x0 + x1 * x1 + x2 * x2 + x3 * x3;
    for (int off = 32; off; off >>= 1) {
        sum += __shfl_down(sum, off);
        sq  += __shfl_down(sq, off);
    }
    sum = __shfl(sum, 0);
    sq  = __shfl(sq, 0);
    const float mu = sum * (1.f / 256.f);
    const float var = sq * (1.f / 256.f) - mu * mu;
    const float rstd = rsqrtf(var + 1e-5f);
    float* orow = out + (long)(r0 + w) * Dc;
    orow[lane]       = (x0 - mu) * rstd * gamma[lane]       + beta[lane];
    orow[lane + 64]  = (x1 - mu) * rstd * gamma[lane + 64]  + beta[lane + 64];
    orow[lane + 128] = (x2 - mu) * rstd * gamma[lane + 128] + beta[lane + 128];
    orow[lane + 192] = (x3 - mu) * rstd * gamma[lane + 192] + beta[lane + 192];
}

// ---------------------------------------------------------------------------
extern "C" void kernel_launch(void* const* d_in, const int* in_sizes, int n_in,
                              void* d_out, int out_size, void* d_ws, size_t ws_size,
                              hipStream_t stream)
{
    const float* query   = (const float*)d_in[0];
    const float* key_    = (const float*)d_in[1];
    const float* value   = (const float*)d_in[2];
    const unsigned int* mask = (const unsigned int*)d_in[3];
    const float* relation = (const float*)d_in[4];
    const float* Wq  = (const float*)d_in[5];
    const float* Wk  = (const float*)d_in[6];
    const float* Wv  = (const float*)d_in[7];
    const float* Wfc = (const float*)d_in[8];
    const float* bfc = (const float*)d_in[9];
    const float* gamma = (const float*)d_in[10];
    const float* beta  = (const float*)d_in[11];

    float* out_ln   = (float*)d_out;
    float* out_attn = (float*)d_out + (size_t)Bc * Sc * Dc;

    char* ws = (char*)d_ws;
    _Float16* Qb   = (_Float16*)(ws + 0);          //  2 MB [BH][S][32]
    _Float16* Kt   = (_Float16*)(ws + 2097152);    //  2 MB [B][H][32][S]
    _Float16* Vt   = (_Float16*)(ws + 4194304);    //  2 MB [BH][32][S]
    _Float16* relT = (_Float16*)(ws + 6291456);    // 16.8 MB [B][S][S] (n,k)
    _Float16* KRT  = (_Float16*)(ws + 23068672);   //  2 MB [B][S][256] (n, hd)
    float*    attw = (float*)   (ws + 25165824);   //  4 MB [B*S][256]
    unsigned int* mbits = (unsigned int*)(ws + 29360128); // 1 MB [B][S][S/32]

    proj3_kernel<<<dim3(Bc * Sc / 8, 3), 256, 0, stream>>>(
        query, key_, value, Wq, Wk, Wv, Qb, Kt, Vt);
    relT_kernel<<<dim3(Sc / 64, Sc / 64, Bc), 256, 0, stream>>>(relation, relT);
    maskpack_kernel<<<dim3(Bc * Sc * Sc / 32 / 256), 256, 0, stream>>>(mask, mbits);
    kr_kernel<<<dim3(4, Sc / 64, Bc), 256, 0, stream>>>(relT, Kt, KRT);
    fused_attn_kernel<<<dim3(Sc / 64, BH), 256, 0, stream>>>(
        Qb, KRT, Vt, mbits, out_attn, attw);
    out_kernel<<<dim3(Bc * Sc / 4), 256, 0, stream>>>(attw, Wfc, bfc, query,
                                                      gamma, beta, out_ln);
}

// Round 7
// 207.994 us; speedup vs baseline: 1.3292x; 1.3292x over previous
//
#include <hip/hip_runtime.h>

// Problem constants
constexpr int Bc = 2, Sc = 2048, Dc = 256, Hc = 8, DKc = 32;
constexpr int BH = Bc * Hc;

typedef _Float16 f16x8 __attribute__((ext_vector_type(8)));
typedef _Float16 f16x4 __attribute__((ext_vector_type(4)));
typedef float    f32x4 __attribute__((ext_vector_type(4)));

// ---------------------------------------------------------------------------
// K1: three projections in one launch (z = 0:Q, 1:K^T, 2:V^T)
// ---------------------------------------------------------------------------
__global__ __launch_bounds__(256) void proj3_kernel(
    const float* __restrict__ query, const float* __restrict__ key_,
    const float* __restrict__ value, const float* __restrict__ Wq,
    const float* __restrict__ Wk, const float* __restrict__ Wv,
    _Float16* __restrict__ Qb, _Float16* __restrict__ Kt,
    _Float16* __restrict__ Vt)
{
    constexpr int ROWS = 8;
    __shared__ float xs[ROWS][Dc];
    const int z = blockIdx.y;
    const float* X = (z == 0) ? query : (z == 1) ? key_ : value;
    const float* W = (z == 0) ? Wq : (z == 1) ? Wk : Wv;
    _Float16* out = (z == 0) ? Qb : (z == 1) ? Kt : Vt;
    const int vtrans = (z != 0);
    const float scale = (z == 0) ? 0.17677669529663689f : 1.0f;

    const int r0 = blockIdx.x * ROWS;
    const int t = threadIdx.x;
    #pragma unroll
    for (int i = 0; i < ROWS; ++i)
        xs[i][t] = X[(long)(r0 + i) * Dc + t];
    __syncthreads();
    float acc[ROWS];
    #pragma unroll
    for (int i = 0; i < ROWS; ++i) acc[i] = 0.f;
    for (int d = 0; d < Dc; ++d) {
        float w = W[d * Dc + t];
        #pragma unroll
        for (int i = 0; i < ROWS; ++i) acc[i] = fmaf(xs[i][d], w, acc[i]);
    }
    const int h = t >> 5, dk = t & 31;
    #pragma unroll
    for (int i = 0; i < ROWS; ++i) {
        int row = r0 + i;
        int b = row / Sc, s = row % Sc;
        long idx = vtrans ? (((long)(b * Hc + h) * DKc + dk) * Sc + s)
                          : (((long)(b * Hc + h) * Sc + s) * DKc + dk);
        out[idx] = (_Float16)(acc[i] * scale);
    }
}

// ---------------------------------------------------------------------------
// K1b: relT[b][n][k] = relation[b][k][n]  (f32 -> f16, 64x64 LDS transpose)
// ---------------------------------------------------------------------------
__global__ __launch_bounds__(256) void relT_kernel(
    const float* __restrict__ rel, _Float16* __restrict__ relT)
{
    __shared__ float tile[64][65];
    const int b = blockIdx.z;
    const int k0 = blockIdx.y * 64, n0 = blockIdx.x * 64;
    const int tx = threadIdx.x & 63, ty = threadIdx.x >> 6;
    const float* src = rel + (long)b * Sc * Sc;
    #pragma unroll
    for (int i = 0; i < 16; ++i) {
        int k = i * 4 + ty;
        tile[k][tx] = src[(long)(k0 + k) * Sc + n0 + tx];
    }
    __syncthreads();
    _Float16* dst = relT + (long)b * Sc * Sc;
    #pragma unroll
    for (int i = 0; i < 16; ++i) {
        int n = i * 4 + ty;
        dst[(long)(n0 + n) * Sc + k0 + tx] = (_Float16)tile[tx][n];
    }
}

// ---------------------------------------------------------------------------
// K1c: pack mask bytes (0/1) into bits.
// ---------------------------------------------------------------------------
__global__ __launch_bounds__(256) void maskpack_kernel(
    const unsigned int* __restrict__ m, unsigned int* __restrict__ out)
{
    const int idx = blockIdx.x * 256 + threadIdx.x;
    const uint4 a = ((const uint4*)m)[idx * 2];
    const uint4 b = ((const uint4*)m)[idx * 2 + 1];
    unsigned int ws[8] = {a.x, a.y, a.z, a.w, b.x, b.y, b.z, b.w};
    unsigned int r = 0;
    #pragma unroll
    for (int j = 0; j < 8; ++j) {
        unsigned int nib = (ws[j] | (ws[j] >> 7) | (ws[j] >> 14) | (ws[j] >> 21)) & 0xFu;
        r |= nib << (4 * j);
    }
    out[idx] = r;
}

// ---------------------------------------------------------------------------
// K2: KR GEMM.  KRT[b][n][hd] = sum_k relT[b][n][k] * Kt[b][hd][k]
// BM=BN=64, BK=64, 4 waves (2x2) each 32x32 quadrant -> 256 blocks.
// ---------------------------------------------------------------------------
__global__ __launch_bounds__(256) void kr_kernel(
    const _Float16* __restrict__ relT, const _Float16* __restrict__ Kt,
    _Float16* __restrict__ KRT)
{
    constexpr int LDK = 72;
    __shared__ _Float16 As[64][LDK];
    __shared__ _Float16 Bs[64][LDK];
    const int b = blockIdx.z;
    const int m0 = blockIdx.y * 64;
    const int n0 = blockIdx.x * 64;
    const _Float16* Ap = relT + (long)b * Sc * Sc;
    const _Float16* Bp = Kt + (long)b * Hc * DKc * Sc;
    const int t = threadIdx.x;
    const int lane = t & 63, wave = t >> 6;
    const int wr = wave >> 1, wc = wave & 1;
    const int c = lane & 15, g = lane >> 4;
    const int lrow = t >> 2;
    const int lcol = (t & 3) * 16;
    f32x4 acc[2][2] = {};
    for (int k0 = 0; k0 < Sc; k0 += 64) {
        *(f16x8*)&As[lrow][lcol]     = *(const f16x8*)&Ap[(long)(m0 + lrow) * Sc + k0 + lcol];
        *(f16x8*)&As[lrow][lcol + 8] = *(const f16x8*)&Ap[(long)(m0 + lrow) * Sc + k0 + lcol + 8];
        *(f16x8*)&Bs[lrow][lcol]     = *(const f16x8*)&Bp[(long)(n0 + lrow) * Sc + k0 + lcol];
        *(f16x8*)&Bs[lrow][lcol + 8] = *(const f16x8*)&Bp[(long)(n0 + lrow) * Sc + k0 + lcol + 8];
        __syncthreads();
        #pragma unroll
        for (int kk = 0; kk < 2; ++kk) {
            const int kb = kk * 32 + g * 8;
            f16x8 af[2], bf[2];
            #pragma unroll
            for (int m = 0; m < 2; ++m)
                af[m] = *(const f16x8*)&As[wr * 32 + m * 16 + c][kb];
            #pragma unroll
            for (int n = 0; n < 2; ++n)
                bf[n] = *(const f16x8*)&Bs[wc * 32 + n * 16 + c][kb];
            #pragma unroll
            for (int m = 0; m < 2; ++m)
                #pragma unroll
                for (int n = 0; n < 2; ++n)
                    acc[m][n] = __builtin_amdgcn_mfma_f32_16x16x32_f16(
                        af[m], bf[n], acc[m][n], 0, 0, 0);
        }
        __syncthreads();
    }
    _Float16* outp = KRT + (long)b * Sc * 256;
    #pragma unroll
    for (int m = 0; m < 2; ++m)
        #pragma unroll
        for (int n = 0; n < 2; ++n)
            #pragma unroll
            for (int i = 0; i < 4; ++i) {
                int row = m0 + wr * 32 + m * 16 + g * 4 + i;
                int col = n0 + wc * 32 + n * 16 + c;
                outp[(long)row * 256 + col] = (_Float16)acc[m][n][i];
            }
}

// ---------------------------------------------------------------------------
// K3a: esum + PV pass.  Per block: 64 q-rows, full n loop.
// s = mfma(KR, Q); p = exp (masked -> 0); esum accumulate; p -> f16 LDS -> PV.
// Outputs: rinv[bh][q], normalized attw.  NO attn stores here.
// ---------------------------------------------------------------------------
__global__ __launch_bounds__(256) void attn_pv_kernel(
    const _Float16* __restrict__ Qb,   // [BH][S][32], pre-scaled
    const _Float16* __restrict__ KRT,  // [B][S][256]
    const _Float16* __restrict__ Vt,   // [BH][32][S]
    const unsigned int* __restrict__ mbits, // [B][S][S/32]
    float* __restrict__ rinvg,         // [BH][S]
    float* __restrict__ attw)          // [B*S][256]
{
    constexpr int NT = 128, LDP = 136;
    __shared__ _Float16 p_lds[64][LDP];
    const int bh = blockIdx.y;
    const int b = bh >> 3, h = bh & 7;
    const int q0 = blockIdx.x * 64;
    const int t = threadIdx.x, lane = t & 63, w = t >> 6;
    const int c = lane & 15, g = lane >> 4;
    const int q = q0 + w * 16 + c;
    const f16x8 qf = *(const f16x8*)&Qb[((long)bh * Sc + q) * DKc + g * 8];
    const _Float16* krt = KRT + (long)b * Sc * 256 + h * 32;
    const unsigned int* mbitrow = mbits + ((long)b * Sc + q) * (Sc / 32);
    const f32x4 zero = {};
    f32x4 acc[2] = {};
    float esum = 0.f;

    for (int nt = 0; nt < Sc / NT; ++nt) {
        const int n0 = nt * NT;
        f32x4 s[8];
        #pragma unroll
        for (int nf = 0; nf < 8; ++nf) {
            f16x8 kf = *(const f16x8*)&krt[(long)(n0 + nf * 16 + c) * 256 + g * 8];
            s[nf] = __builtin_amdgcn_mfma_f32_16x16x32_f16(kf, qf, zero, 0, 0, 0);
        }
        const uint4 mq = *(const uint4*)&mbitrow[nt * 4];
        const unsigned int mwv[4] = {mq.x, mq.y, mq.z, mq.w};
        #pragma unroll
        for (int nf = 0; nf < 8; ++nf) {
            const unsigned int bits = mwv[nf >> 1] >> ((nf & 1) * 16 + g * 4);
            f16x4 pv;
            #pragma unroll
            for (int i = 0; i < 4; ++i) {
                float p = ((bits >> i) & 1u) ? 0.f : __expf(s[nf][i]);
                esum += p;
                pv[i] = (_Float16)p;
            }
            *(f16x4*)&p_lds[w * 16 + c][nf * 16 + g * 4] = pv;
        }
        #pragma unroll
        for (int ks = 0; ks < 4; ++ks) {
            f16x8 af = *(const f16x8*)&p_lds[w * 16 + c][ks * 32 + g * 8];
            #pragma unroll
            for (int nb = 0; nb < 2; ++nb) {
                f16x8 vf = *(const f16x8*)&Vt[((long)bh * DKc + nb * 16 + c) * Sc + n0 + ks * 32 + g * 8];
                acc[nb] = __builtin_amdgcn_mfma_f32_16x16x32_f16(af, vf, acc[nb], 0, 0, 0);
            }
        }
    }
    esum += __shfl_xor(esum, 16);
    esum += __shfl_xor(esum, 32);
    const float rinv = 1.f / esum;
    if (lane < 16)
        rinvg[(long)bh * Sc + q0 + w * 16 + lane] = rinv;
    #pragma unroll
    for (int nb = 0; nb < 2; ++nb)
        #pragma unroll
        for (int i = 0; i < 4; ++i) {
            const float rs = __shfl(rinv, g * 4 + i);
            attw[((long)(b * Sc + q0 + w * 16 + g * 4 + i)) * Dc + h * 32 + nb * 16 + c]
                = acc[nb][i] * rs;
        }
}

// ---------------------------------------------------------------------------
// K3b: attn store pass.  Grid (n-tile, q-tile, bh) = (16, 32, 16) = 8192
// blocks.  Per block: 64q x 128n tile; recompute s (8 MFMA), p = exp*rinv
// (masked -> 0), stage in wave-private LDS, 512B-contiguous NT stores.
// ---------------------------------------------------------------------------
__global__ __launch_bounds__(256) void attn_store_kernel(
    const _Float16* __restrict__ Qb,   // [BH][S][32]
    const _Float16* __restrict__ KRT,  // [B][S][256]
    const unsigned int* __restrict__ mbits, // [B][S][S/32]
    const float* __restrict__ rinvg,   // [BH][S]
    float* __restrict__ attn_out)      // [BH][S][S]
{
    constexpr int LDA = 132;
    __shared__ float a_lds[4][16][LDA];
    const int nt = blockIdx.x;          // n tile (128 wide)
    const int q0 = blockIdx.y * 64;
    const int bh = blockIdx.z;
    const int b = bh >> 3, h = bh & 7;
    const int t = threadIdx.x, lane = t & 63, w = t >> 6;
    const int c = lane & 15, g = lane >> 4;
    const int q = q0 + w * 16 + c;
    const int n0 = nt * 128;
    const f16x8 qf = *(const f16x8*)&Qb[((long)bh * Sc + q) * DKc + g * 8];
    const _Float16* krt = KRT + (long)b * Sc * 256 + h * 32;
    const float rinv = rinvg[(long)bh * Sc + q];
    const f32x4 zero = {};

    f32x4 s[8];
    #pragma unroll
    for (int nf = 0; nf < 8; ++nf) {
        f16x8 kf = *(const f16x8*)&krt[(long)(n0 + nf * 16 + c) * 256 + g * 8];
        s[nf] = __builtin_amdgcn_mfma_f32_16x16x32_f16(kf, qf, zero, 0, 0, 0);
    }
    const uint4 mq = *(const uint4*)&mbits[((long)b * Sc + q) * (Sc / 32) + nt * 4];
    const unsigned int mwv[4] = {mq.x, mq.y, mq.z, mq.w};
    #pragma unroll
    for (int nf = 0; nf < 8; ++nf) {
        const unsigned int bits = mwv[nf >> 1] >> ((nf & 1) * 16 + g * 4);
        f32x4 av;
        #pragma unroll
        for (int i = 0; i < 4; ++i)
            av[i] = ((bits >> i) & 1u) ? 0.f : __expf(s[nf][i]) * rinv;
        *(f32x4*)&a_lds[w][c][nf * 16 + g * 4] = av;
    }
    // wave-private: no barrier needed
    float* aoutw = attn_out + (long)bh * Sc * Sc
                 + (long)(q0 + w * 16 + (lane >> 5)) * Sc + (lane & 31) * 4 + n0;
    #pragma unroll
    for (int r2 = 0; r2 < 8; ++r2) {
        f32x4 v = *(const f32x4*)&a_lds[w][r2 * 2 + (lane >> 5)][(lane & 31) * 4];
        __builtin_nontemporal_store(v, (f32x4*)&aoutw[(long)(r2 * 2) * Sc]);
    }
}

// ---------------------------------------------------------------------------
// K4: out = LayerNorm(att @ Wfc + bfc + query) * gamma + beta
// ---------------------------------------------------------------------------
__global__ __launch_bounds__(256) void out_kernel(
    const float* __restrict__ att, const float* __restrict__ Wfc,
    const float* __restrict__ bfc, const float* __restrict__ query,
    const float* __restrict__ gamma, const float* __restrict__ beta,
    float* __restrict__ out)
{
    __shared__ float xs[4][Dc];
    __shared__ float ys[4][Dc];
    const int r0 = blockIdx.x * 4;
    const int t = threadIdx.x;
    #pragma unroll
    for (int i = 0; i < 4; ++i) xs[i][t] = att[(long)(r0 + i) * Dc + t];
    __syncthreads();
    float acc[4] = {0.f, 0.f, 0.f, 0.f};
    for (int d = 0; d < Dc; ++d) {
        float wv = Wfc[d * Dc + t];
        #pragma unroll
        for (int i = 0; i < 4; ++i) acc[i] = fmaf(xs[i][d], wv, acc[i]);
    }
    const float bias = bfc[t];
    #pragma unroll
    for (int i = 0; i < 4; ++i)
        ys[i][t] = acc[i] + bias + query[(long)(r0 + i) * Dc + t];
    __syncthreads();
    const int w = t >> 6, lane = t & 63;
    float x0 = ys[w][lane], x1 = ys[w][lane + 64];
    float x2 = ys[w][lane + 128], x3 = ys[w][lane + 192];
    float sum = x0 + x1 + x2 + x3;
    float sq = x0 * x0 + x1 * x1 + x2 * x2 + x3 * x3;
    for (int off = 32; off; off >>= 1) {
        sum += __shfl_down(sum, off);
        sq  += __shfl_down(sq, off);
    }
    sum = __shfl(sum, 0);
    sq  = __shfl(sq, 0);
    const float mu = sum * (1.f / 256.f);
    const float var = sq * (1.f / 256.f) - mu * mu;
    const float rstd = rsqrtf(var + 1e-5f);
    float* orow = out + (long)(r0 + w) * Dc;
    orow[lane]       = (x0 - mu) * rstd * gamma[lane]       + beta[lane];
    orow[lane + 64]  = (x1 - mu) * rstd * gamma[lane + 64]  + beta[lane + 64];
    orow[lane + 128] = (x2 - mu) * rstd * gamma[lane + 128] + beta[lane + 128];
    orow[lane + 192] = (x3 - mu) * rstd * gamma[lane + 192] + beta[lane + 192];
}

// ---------------------------------------------------------------------------
extern "C" void kernel_launch(void* const* d_in, const int* in_sizes, int n_in,
                              void* d_out, int out_size, void* d_ws, size_t ws_size,
                              hipStream_t stream)
{
    const float* query   = (const float*)d_in[0];
    const float* key_    = (const float*)d_in[1];
    const float* value   = (const float*)d_in[2];
    const unsigned int* mask = (const unsigned int*)d_in[3];
    const float* relation = (const float*)d_in[4];
    const float* Wq  = (const float*)d_in[5];
    const float* Wk  = (const float*)d_in[6];
    const float* Wv  = (const float*)d_in[7];
    const float* Wfc = (const float*)d_in[8];
    const float* bfc = (const float*)d_in[9];
    const float* gamma = (const float*)d_in[10];
    const float* beta  = (const float*)d_in[11];

    float* out_ln   = (float*)d_out;
    float* out_attn = (float*)d_out + (size_t)Bc * Sc * Dc;

    char* ws = (char*)d_ws;
    _Float16* Qb   = (_Float16*)(ws + 0);          //  2 MB [BH][S][32]
    _Float16* Kt   = (_Float16*)(ws + 2097152);    //  2 MB [B][H][32][S]
    _Float16* Vt   = (_Float16*)(ws + 4194304);    //  2 MB [BH][32][S]
    _Float16* relT = (_Float16*)(ws + 6291456);    // 16.8 MB [B][S][S] (n,k)
    _Float16* KRT  = (_Float16*)(ws + 23068672);   //  2 MB [B][S][256] (n, hd)
    float*    attw = (float*)   (ws + 25165824);   //  4 MB [B*S][256]
    unsigned int* mbits = (unsigned int*)(ws + 29360128); // 1 MB [B][S][S/32]
    float*    rinvg = (float*)  (ws + 30408704);   // 128 KB [BH][S]

    proj3_kernel<<<dim3(Bc * Sc / 8, 3), 256, 0, stream>>>(
        query, key_, value, Wq, Wk, Wv, Qb, Kt, Vt);
    relT_kernel<<<dim3(Sc / 64, Sc / 64, Bc), 256, 0, stream>>>(relation, relT);
    maskpack_kernel<<<dim3(Bc * Sc * Sc / 32 / 256), 256, 0, stream>>>(mask, mbits);
    kr_kernel<<<dim3(4, Sc / 64, Bc), 256, 0, stream>>>(relT, Kt, KRT);
    attn_pv_kernel<<<dim3(Sc / 64, BH), 256, 0, stream>>>(
        Qb, KRT, Vt, mbits, rinvg, attw);
    attn_store_kernel<<<dim3(Sc / 128, Sc / 64, BH), 256, 0, stream>>>(
        Qb, KRT, mbits, rinvg, out_attn);
    out_kernel<<<dim3(Bc * Sc / 4), 256, 0, stream>>>(attw, Wfc, bfc, query,
                                                      gamma, beta, out_ln);
}

// Round 8
// 206.835 us; speedup vs baseline: 1.3367x; 1.0056x over previous
//
#include <hip/hip_runtime.h>

// Problem constants
constexpr int Bc = 2, Sc = 2048, Dc = 256, Hc = 8, DKc = 32;
constexpr int BH = Bc * Hc;

typedef _Float16 f16x8 __attribute__((ext_vector_type(8)));
typedef _Float16 f16x4 __attribute__((ext_vector_type(4)));
typedef float    f32x4 __attribute__((ext_vector_type(4)));

// ---------------------------------------------------------------------------
// K1: three projections in one launch (z = 0:Q, 1:K^T, 2:V^T)
// ---------------------------------------------------------------------------
__global__ __launch_bounds__(256) void proj3_kernel(
    const float* __restrict__ query, const float* __restrict__ key_,
    const float* __restrict__ value, const float* __restrict__ Wq,
    const float* __restrict__ Wk, const float* __restrict__ Wv,
    _Float16* __restrict__ Qb, _Float16* __restrict__ Kt,
    _Float16* __restrict__ Vt)
{
    constexpr int ROWS = 8;
    __shared__ float xs[ROWS][Dc];
    const int z = blockIdx.y;
    const float* X = (z == 0) ? query : (z == 1) ? key_ : value;
    const float* W = (z == 0) ? Wq : (z == 1) ? Wk : Wv;
    _Float16* out = (z == 0) ? Qb : (z == 1) ? Kt : Vt;
    const int vtrans = (z != 0);
    const float scale = (z == 0) ? 0.17677669529663689f : 1.0f;

    const int r0 = blockIdx.x * ROWS;
    const int t = threadIdx.x;
    #pragma unroll
    for (int i = 0; i < ROWS; ++i)
        xs[i][t] = X[(long)(r0 + i) * Dc + t];
    __syncthreads();
    float acc[ROWS];
    #pragma unroll
    for (int i = 0; i < ROWS; ++i) acc[i] = 0.f;
    for (int d = 0; d < Dc; ++d) {
        float w = W[d * Dc + t];
        #pragma unroll
        for (int i = 0; i < ROWS; ++i) acc[i] = fmaf(xs[i][d], w, acc[i]);
    }
    const int h = t >> 5, dk = t & 31;
    #pragma unroll
    for (int i = 0; i < ROWS; ++i) {
        int row = r0 + i;
        int b = row / Sc, s = row % Sc;
        long idx = vtrans ? (((long)(b * Hc + h) * DKc + dk) * Sc + s)
                          : (((long)(b * Hc + h) * Sc + s) * DKc + dk);
        out[idx] = (_Float16)(acc[i] * scale);
    }
}

// ---------------------------------------------------------------------------
// K1b: relT[b][n][k] = relation[b][k][n]  — vectorized: f32x4 loads,
// LDS transpose, f16x4 stores.
// ---------------------------------------------------------------------------
__global__ __launch_bounds__(256) void relT_kernel(
    const float* __restrict__ rel, _Float16* __restrict__ relT)
{
    __shared__ float tile[64][65];
    const int b = blockIdx.z;
    const int k0 = blockIdx.y * 64, n0 = blockIdx.x * 64;
    const int t = threadIdx.x;
    const int r = t >> 4;            // 0..15
    const int c4 = (t & 15) * 4;     // 0..60
    const float* src = rel + (long)b * Sc * Sc;
    #pragma unroll
    for (int i = 0; i < 4; ++i) {
        f32x4 v = *(const f32x4*)&src[(long)(k0 + i * 16 + r) * Sc + n0 + c4];
        *(f32x4*)&tile[i * 16 + r][c4] = v;
    }
    __syncthreads();
    _Float16* dst = relT + (long)b * Sc * Sc;
    #pragma unroll
    for (int i = 0; i < 4; ++i) {
        const int n = i * 16 + r;
        f16x4 o;
        #pragma unroll
        for (int e = 0; e < 4; ++e) o[e] = (_Float16)tile[c4 + e][n];
        *(f16x4*)&dst[(long)(n0 + n) * Sc + k0 + c4] = o;
    }
}

// ---------------------------------------------------------------------------
// K1c: pack mask bytes (0/1) into bits.
// ---------------------------------------------------------------------------
__global__ __launch_bounds__(256) void maskpack_kernel(
    const unsigned int* __restrict__ m, unsigned int* __restrict__ out)
{
    const int idx = blockIdx.x * 256 + threadIdx.x;
    const uint4 a = ((const uint4*)m)[idx * 2];
    const uint4 b = ((const uint4*)m)[idx * 2 + 1];
    unsigned int ws[8] = {a.x, a.y, a.z, a.w, b.x, b.y, b.z, b.w};
    unsigned int r = 0;
    #pragma unroll
    for (int j = 0; j < 8; ++j) {
        unsigned int nib = (ws[j] | (ws[j] >> 7) | (ws[j] >> 14) | (ws[j] >> 21)) & 0xFu;
        r |= nib << (4 * j);
    }
    out[idx] = r;
}

// ---------------------------------------------------------------------------
// K2: KR GEMM, k-split x2.  KRp[ks][b][n][hd] = sum_{k in half ks} relT*Kt
// BM=BN=64, BK=64, 4 waves (2x2); grid (4 hd, 32 n, b*2+ks) = 512 blocks.
// ---------------------------------------------------------------------------
__global__ __launch_bounds__(256) void kr_kernel(
    const _Float16* __restrict__ relT, const _Float16* __restrict__ Kt,
    float* __restrict__ KRp)
{
    constexpr int LDK = 72;
    __shared__ _Float16 As[64][LDK];
    __shared__ _Float16 Bs[64][LDK];
    const int z = blockIdx.z;
    const int b = z >> 1, ks = z & 1;
    const int m0 = blockIdx.y * 64;
    const int n0 = blockIdx.x * 64;
    const _Float16* Ap = relT + (long)b * Sc * Sc;
    const _Float16* Bp = Kt + (long)b * Hc * DKc * Sc;
    const int t = threadIdx.x;
    const int lane = t & 63, wave = t >> 6;
    const int wr = wave >> 1, wc = wave & 1;
    const int c = lane & 15, g = lane >> 4;
    const int lrow = t >> 2;
    const int lcol = (t & 3) * 16;
    f32x4 acc[2][2] = {};
    for (int k0 = ks * 1024; k0 < ks * 1024 + 1024; k0 += 64) {
        *(f16x8*)&As[lrow][lcol]     = *(const f16x8*)&Ap[(long)(m0 + lrow) * Sc + k0 + lcol];
        *(f16x8*)&As[lrow][lcol + 8] = *(const f16x8*)&Ap[(long)(m0 + lrow) * Sc + k0 + lcol + 8];
        *(f16x8*)&Bs[lrow][lcol]     = *(const f16x8*)&Bp[(long)(n0 + lrow) * Sc + k0 + lcol];
        *(f16x8*)&Bs[lrow][lcol + 8] = *(const f16x8*)&Bp[(long)(n0 + lrow) * Sc + k0 + lcol + 8];
        __syncthreads();
        #pragma unroll
        for (int kk = 0; kk < 2; ++kk) {
            const int kb = kk * 32 + g * 8;
            f16x8 af[2], bf[2];
            #pragma unroll
            for (int m = 0; m < 2; ++m)
                af[m] = *(const f16x8*)&As[wr * 32 + m * 16 + c][kb];
            #pragma unroll
            for (int n = 0; n < 2; ++n)
                bf[n] = *(const f16x8*)&Bs[wc * 32 + n * 16 + c][kb];
            #pragma unroll
            for (int m = 0; m < 2; ++m)
                #pragma unroll
                for (int n = 0; n < 2; ++n)
                    acc[m][n] = __builtin_amdgcn_mfma_f32_16x16x32_f16(
                        af[m], bf[n], acc[m][n], 0, 0, 0);
        }
        __syncthreads();
    }
    float* outp = KRp + ((long)ks * Bc + b) * Sc * 256;
    #pragma unroll
    for (int m = 0; m < 2; ++m)
        #pragma unroll
        for (int n = 0; n < 2; ++n)
            #pragma unroll
            for (int i = 0; i < 4; ++i) {
                int row = m0 + wr * 32 + m * 16 + g * 4 + i;
                int col = n0 + wc * 32 + n * 16 + c;
                outp[(long)row * 256 + col] = acc[m][n][i];
            }
}

// ---------------------------------------------------------------------------
// K2b: KRT = f16(KRp[0] + KRp[1])
// ---------------------------------------------------------------------------
__global__ __launch_bounds__(256) void krc_kernel(
    const float* __restrict__ KRp, _Float16* __restrict__ KRT)
{
    const long idx = ((long)blockIdx.x * 256 + threadIdx.x) * 4;
    const long half = (long)Bc * Sc * 256;
    f32x4 a = *(const f32x4*)&KRp[idx];
    f32x4 b = *(const f32x4*)&KRp[half + idx];
    f16x4 o;
    #pragma unroll
    for (int i = 0; i < 4; ++i) o[i] = (_Float16)(a[i] + b[i]);
    *(f16x4*)&KRT[idx] = o;
}

// ---------------------------------------------------------------------------
// K3a: esum + PV pass, n-split x2.  grid (32 q-tiles, BH, 2 ns).
// Each block: 64 q-rows, n in [ns*1024, ns*1024+1024).
// Writes partial esum_p[ns][bh][q] and UNNORMALIZED accp[ns][bh][q][32].
// ---------------------------------------------------------------------------
__global__ __launch_bounds__(256) void attn_pv_kernel(
    const _Float16* __restrict__ Qb,   // [BH][S][32], pre-scaled
    const _Float16* __restrict__ KRT,  // [B][S][256]
    const _Float16* __restrict__ Vt,   // [BH][32][S]
    const unsigned int* __restrict__ mbits, // [B][S][S/32]
    float* __restrict__ esum_p,        // [2][BH][S]
    float* __restrict__ accp)          // [2][BH][S][32]
{
    constexpr int NT = 128, LDP = 136;
    __shared__ _Float16 p_lds[64][LDP];
    const int bh = blockIdx.y;
    const int ns = blockIdx.z;
    const int b = bh >> 3, h = bh & 7;
    const int q0 = blockIdx.x * 64;
    const int t = threadIdx.x, lane = t & 63, w = t >> 6;
    const int c = lane & 15, g = lane >> 4;
    const int q = q0 + w * 16 + c;
    const f16x8 qf = *(const f16x8*)&Qb[((long)bh * Sc + q) * DKc + g * 8];
    const _Float16* krt = KRT + (long)b * Sc * 256 + h * 32;
    const unsigned int* mbitrow = mbits + ((long)b * Sc + q) * (Sc / 32);
    const f32x4 zero = {};
    f32x4 acc[2] = {};
    float esum = 0.f;

    for (int nt = ns * (1024 / NT); nt < (ns + 1) * (1024 / NT); ++nt) {
        const int n0 = nt * NT;
        f32x4 s[8];
        #pragma unroll
        for (int nf = 0; nf < 8; ++nf) {
            f16x8 kf = *(const f16x8*)&krt[(long)(n0 + nf * 16 + c) * 256 + g * 8];
            s[nf] = __builtin_amdgcn_mfma_f32_16x16x32_f16(kf, qf, zero, 0, 0, 0);
        }
        const uint4 mq = *(const uint4*)&mbitrow[nt * 4];
        const unsigned int mwv[4] = {mq.x, mq.y, mq.z, mq.w};
        #pragma unroll
        for (int nf = 0; nf < 8; ++nf) {
            const unsigned int bits = mwv[nf >> 1] >> ((nf & 1) * 16 + g * 4);
            f16x4 pv;
            #pragma unroll
            for (int i = 0; i < 4; ++i) {
                float p = ((bits >> i) & 1u) ? 0.f : __expf(s[nf][i]);
                esum += p;
                pv[i] = (_Float16)p;
            }
            *(f16x4*)&p_lds[w * 16 + c][nf * 16 + g * 4] = pv;
        }
        #pragma unroll
        for (int ks = 0; ks < 4; ++ks) {
            f16x8 af = *(const f16x8*)&p_lds[w * 16 + c][ks * 32 + g * 8];
            #pragma unroll
            for (int nb = 0; nb < 2; ++nb) {
                f16x8 vf = *(const f16x8*)&Vt[((long)bh * DKc + nb * 16 + c) * Sc + n0 + ks * 32 + g * 8];
                acc[nb] = __builtin_amdgcn_mfma_f32_16x16x32_f16(af, vf, acc[nb], 0, 0, 0);
            }
        }
    }
    esum += __shfl_xor(esum, 16);
    esum += __shfl_xor(esum, 32);
    if (lane < 16)
        esum_p[((long)ns * BH + bh) * Sc + q0 + w * 16 + lane] = esum;
    #pragma unroll
    for (int nb = 0; nb < 2; ++nb)
        #pragma unroll
        for (int i = 0; i < 4; ++i) {
            const long qrow = q0 + w * 16 + g * 4 + i;
            accp[(((long)ns * BH + bh) * Sc + qrow) * 32 + nb * 16 + c] = acc[nb][i];
        }
}

// ---------------------------------------------------------------------------
// K3c: combine partials -> attw (normalized) + rinvg.
// Block: 8 q-rows x 32 hd.  grid BH*S/8 = 4096.
// ---------------------------------------------------------------------------
__global__ __launch_bounds__(256) void pvc_kernel(
    const float* __restrict__ esum_p,  // [2][BH][S]
    const float* __restrict__ accp,    // [2][BH][S][32]
    float* __restrict__ attw,          // [B*S][256]
    float* __restrict__ rinvg)         // [BH][S]
{
    const int t = threadIdx.x;
    const int qi = t >> 5, hd = t & 31;
    const long row = (long)blockIdx.x * 8 + qi;   // bh*S + q
    const int bh = (int)(row >> 11);
    const int q = (int)(row & (Sc - 1));
    const int b = bh >> 3, h = bh & 7;
    const long half = (long)BH * Sc;
    const float rinv = 1.f / (esum_p[row] + esum_p[half + row]);
    const float a = accp[row * 32 + hd] + accp[half * 32 + row * 32 + hd];
    attw[((long)(b * Sc + q)) * Dc + h * 32 + hd] = a * rinv;
    if (hd == 0) rinvg[row] = rinv;
}

// ---------------------------------------------------------------------------
// K3b: attn store pass.  Grid (16 n-tiles, 32 q-tiles, 16 bh) = 8192 blocks.
// ---------------------------------------------------------------------------
__global__ __launch_bounds__(256) void attn_store_kernel(
    const _Float16* __restrict__ Qb,   // [BH][S][32]
    const _Float16* __restrict__ KRT,  // [B][S][256]
    const unsigned int* __restrict__ mbits, // [B][S][S/32]
    const float* __restrict__ rinvg,   // [BH][S]
    float* __restrict__ attn_out)      // [BH][S][S]
{
    constexpr int LDA = 132;
    __shared__ float a_lds[4][16][LDA];
    const int nt = blockIdx.x;
    const int q0 = blockIdx.y * 64;
    const int bh = blockIdx.z;
    const int b = bh >> 3, h = bh & 7;
    const int t = threadIdx.x, lane = t & 63, w = t >> 6;
    const int c = lane & 15, g = lane >> 4;
    const int q = q0 + w * 16 + c;
    const int n0 = nt * 128;
    const f16x8 qf = *(const f16x8*)&Qb[((long)bh * Sc + q) * DKc + g * 8];
    const _Float16* krt = KRT + (long)b * Sc * 256 + h * 32;
    const float rinv = rinvg[(long)bh * Sc + q];
    const f32x4 zero = {};

    f32x4 s[8];
    #pragma unroll
    for (int nf = 0; nf < 8; ++nf) {
        f16x8 kf = *(const f16x8*)&krt[(long)(n0 + nf * 16 + c) * 256 + g * 8];
        s[nf] = __builtin_amdgcn_mfma_f32_16x16x32_f16(kf, qf, zero, 0, 0, 0);
    }
    const uint4 mq = *(const uint4*)&mbits[((long)b * Sc + q) * (Sc / 32) + nt * 4];
    const unsigned int mwv[4] = {mq.x, mq.y, mq.z, mq.w};
    #pragma unroll
    for (int nf = 0; nf < 8; ++nf) {
        const unsigned int bits = mwv[nf >> 1] >> ((nf & 1) * 16 + g * 4);
        f32x4 av;
        #pragma unroll
        for (int i = 0; i < 4; ++i)
            av[i] = ((bits >> i) & 1u) ? 0.f : __expf(s[nf][i]) * rinv;
        *(f32x4*)&a_lds[w][c][nf * 16 + g * 4] = av;
    }
    float* aoutw = attn_out + (long)bh * Sc * Sc
                 + (long)(q0 + w * 16 + (lane >> 5)) * Sc + (lane & 31) * 4 + n0;
    #pragma unroll
    for (int r2 = 0; r2 < 8; ++r2) {
        f32x4 v = *(const f32x4*)&a_lds[w][r2 * 2 + (lane >> 5)][(lane & 31) * 4];
        __builtin_nontemporal_store(v, (f32x4*)&aoutw[(long)(r2 * 2) * Sc]);
    }
}

// ---------------------------------------------------------------------------
// K4: out = LayerNorm(att @ Wfc + bfc + query) * gamma + beta
// ---------------------------------------------------------------------------
__global__ __launch_bounds__(256) void out_kernel(
    const float* __restrict__ att, const float* __restrict__ Wfc,
    const float* __restrict__ bfc, const float* __restrict__ query,
    const float* __restrict__ gamma, const float* __restrict__ beta,
    float* __restrict__ out)
{
    __shared__ float xs[4][Dc];
    __shared__ float ys[4][Dc];
    const int r0 = blockIdx.x * 4;
    const int t = threadIdx.x;
    #pragma unroll
    for (int i = 0; i < 4; ++i) xs[i][t] = att[(long)(r0 + i) * Dc + t];
    __syncthreads();
    float acc[4] = {0.f, 0.f, 0.f, 0.f};
    for (int d = 0; d < Dc; ++d) {
        float wv = Wfc[d * Dc + t];
        #pragma unroll
        for (int i = 0; i < 4; ++i) acc[i] = fmaf(xs[i][d], wv, acc[i]);
    }
    const float bias = bfc[t];
    #pragma unroll
    for (int i = 0; i < 4; ++i)
        ys[i][t] = acc[i] + bias + query[(long)(r0 + i) * Dc + t];
    __syncthreads();
    const int w = t >> 6, lane = t & 63;
    float x0 = ys[w][lane], x1 = ys[w][lane + 64];
    float x2 = ys[w][lane + 128], x3 = ys[w][lane + 192];
    float sum = x0 + x1 + x2 + x3;
    float sq = x0 * x0 + x1 * x1 + x2 * x2 + x3 * x3;
    for (int off = 32; off; off >>= 1) {
        sum += __shfl_down(sum, off);
        sq  += __shfl_down(sq, off);
    }
    sum = __shfl(sum, 0);
    sq  = __shfl(sq, 0);
    const float mu = sum * (1.f / 256.f);
    const float var = sq * (1.f / 256.f) - mu * mu;
    const float rstd = rsqrtf(var + 1e-5f);
    float* orow = out + (long)(r0 + w) * Dc;
    orow[lane]       = (x0 - mu) * rstd * gamma[lane]       + beta[lane];
    orow[lane + 64]  = (x1 - mu) * rstd * gamma[lane + 64]  + beta[lane + 64];
    orow[lane + 128] = (x2 - mu) * rstd * gamma[lane + 128] + beta[lane + 128];
    orow[lane + 192] = (x3 - mu) * rstd * gamma[lane + 192] + beta[lane + 192];
}

// ---------------------------------------------------------------------------
extern "C" void kernel_launch(void* const* d_in, const int* in_sizes, int n_in,
                              void* d_out, int out_size, void* d_ws, size_t ws_size,
                              hipStream_t stream)
{
    const float* query   = (const float*)d_in[0];
    const float* key_    = (const float*)d_in[1];
    const float* value   = (const float*)d_in[2];
    const unsigned int* mask = (const unsigned int*)d_in[3];
    const float* relation = (const float*)d_in[4];
    const float* Wq  = (const float*)d_in[5];
    const float* Wk  = (const float*)d_in[6];
    const float* Wv  = (const float*)d_in[7];
    const float* Wfc = (const float*)d_in[8];
    const float* bfc = (const float*)d_in[9];
    const float* gamma = (const float*)d_in[10];
    const float* beta  = (const float*)d_in[11];

    float* out_ln   = (float*)d_out;
    float* out_attn = (float*)d_out + (size_t)Bc * Sc * Dc;

    char* ws = (char*)d_ws;
    _Float16* Qb   = (_Float16*)(ws + 0);          //  2 MB [BH][S][32]
    _Float16* Kt   = (_Float16*)(ws + 2097152);    //  2 MB [B][H][32][S]
    _Float16* Vt   = (_Float16*)(ws + 4194304);    //  2 MB [BH][32][S]
    _Float16* relT = (_Float16*)(ws + 6291456);    // 16.8 MB [B][S][S] (n,k)
    _Float16* KRT  = (_Float16*)(ws + 23068672);   //  2 MB [B][S][256]
    float*    attw = (float*)   (ws + 25165824);   //  4 MB [B*S][256]
    unsigned int* mbits = (unsigned int*)(ws + 29360128); // 1 MB
    float*    rinvg = (float*)  (ws + 30408704);   // 128 KB [BH][S]
    float*    KRp   = (float*)  (ws + 30539776);   // 8.4 MB [2][B][S][256]
    float*    esum_p= (float*)  (ws + 38928384);   // 256 KB [2][BH][S]
    float*    accp  = (float*)  (ws + 39190528);   // 8.4 MB [2][BH][S][32]

    proj3_kernel<<<dim3(Bc * Sc / 8, 3), 256, 0, stream>>>(
        query, key_, value, Wq, Wk, Wv, Qb, Kt, Vt);
    relT_kernel<<<dim3(Sc / 64, Sc / 64, Bc), 256, 0, stream>>>(relation, relT);
    maskpack_kernel<<<dim3(Bc * Sc * Sc / 32 / 256), 256, 0, stream>>>(mask, mbits);
    kr_kernel<<<dim3(4, Sc / 64, Bc * 2), 256, 0, stream>>>(relT, Kt, KRp);
    krc_kernel<<<dim3(Bc * Sc * 256 / 4 / 256), 256, 0, stream>>>(KRp, KRT);
    attn_pv_kernel<<<dim3(Sc / 64, BH, 2), 256, 0, stream>>>(
        Qb, KRT, Vt, mbits, esum_p, accp);
    pvc_kernel<<<dim3(BH * Sc / 8), 256, 0, stream>>>(esum_p, accp, attw, rinvg);
    attn_store_kernel<<<dim3(Sc / 128, Sc / 64, BH), 256, 0, stream>>>(
        Qb, KRT, mbits, rinvg, out_attn);
    out_kernel<<<dim3(Bc * Sc / 4), 256, 0, stream>>>(attw, Wfc, bfc, query,
                                                      gamma, beta, out_ln);
}

// Round 9
// 196.868 us; speedup vs baseline: 1.4043x; 1.0506x over previous
//
#include <hip/hip_runtime.h>

// Problem constants
constexpr int Bc = 2, Sc = 2048, Dc = 256, Hc = 8, DKc = 32;
constexpr int BH = Bc * Hc;

typedef _Float16 f16x8 __attribute__((ext_vector_type(8)));
typedef _Float16 f16x4 __attribute__((ext_vector_type(4)));
typedef float    f32x4 __attribute__((ext_vector_type(4)));

// ---------------------------------------------------------------------------
// K1: fused prep.  blocks [0,1536): proj (z=bx/512: 0=Q,1=K^T,2=V^T)
//                  blocks [1536,3584): relT 64x64 transpose tiles
//                  blocks [3584,4096): maskpack
// ---------------------------------------------------------------------------
__global__ __launch_bounds__(256) void prep_kernel(
    const float* __restrict__ query, const float* __restrict__ key_,
    const float* __restrict__ value, const float* __restrict__ Wq,
    const float* __restrict__ Wk, const float* __restrict__ Wv,
    const float* __restrict__ rel, const unsigned int* __restrict__ mask,
    _Float16* __restrict__ Qb, _Float16* __restrict__ Kt,
    _Float16* __restrict__ Vt, _Float16* __restrict__ relT,
    unsigned int* __restrict__ mbits)
{
    __shared__ __align__(16) char smem[16640];
    const int bx = blockIdx.x;
    const int t = threadIdx.x;
    if (bx < 1536) {
        // ---- projection ----
        constexpr int ROWS = 8;
        float (*xs)[Dc] = (float(*)[Dc])smem;
        const int z = bx >> 9;
        const int lb = bx & 511;
        const float* X = (z == 0) ? query : (z == 1) ? key_ : value;
        const float* W = (z == 0) ? Wq : (z == 1) ? Wk : Wv;
        _Float16* out = (z == 0) ? Qb : (z == 1) ? Kt : Vt;
        const int vtrans = (z != 0);
        const float scale = (z == 0) ? 0.17677669529663689f : 1.0f;
        const int r0 = lb * ROWS;
        #pragma unroll
        for (int i = 0; i < ROWS; ++i)
            xs[i][t] = X[(long)(r0 + i) * Dc + t];
        __syncthreads();
        float acc[ROWS];
        #pragma unroll
        for (int i = 0; i < ROWS; ++i) acc[i] = 0.f;
        for (int d = 0; d < Dc; ++d) {
            float w = W[d * Dc + t];
            #pragma unroll
            for (int i = 0; i < ROWS; ++i) acc[i] = fmaf(xs[i][d], w, acc[i]);
        }
        const int h = t >> 5, dk = t & 31;
        #pragma unroll
        for (int i = 0; i < ROWS; ++i) {
            int row = r0 + i;
            int b = row >> 11, s = row & 2047;
            long idx = vtrans ? (((long)(b * Hc + h) * DKc + dk) * Sc + s)
                              : (((long)(b * Hc + h) * Sc + s) * DKc + dk);
            out[idx] = (_Float16)(acc[i] * scale);
        }
    } else if (bx < 3584) {
        // ---- relT: relT[b][n][k] = rel[b][k][n] ----
        float (*tile)[65] = (float(*)[65])smem;
        const int idx = bx - 1536;
        const int b = idx >> 10;
        const int rem = idx & 1023;
        const int k0 = (rem >> 5) * 64, n0 = (rem & 31) * 64;
        const int r = t >> 4;
        const int c4 = (t & 15) * 4;
        const float* src = rel + (long)b * Sc * Sc;
        #pragma unroll
        for (int i = 0; i < 4; ++i) {
            f32x4 v = *(const f32x4*)&src[(long)(k0 + i * 16 + r) * Sc + n0 + c4];
            *(f32x4*)&tile[i * 16 + r][c4] = v;
        }
        __syncthreads();
        _Float16* dst = relT + (long)b * Sc * Sc;
        #pragma unroll
        for (int i = 0; i < 4; ++i) {
            const int n = i * 16 + r;
            f16x4 o;
            #pragma unroll
            for (int e = 0; e < 4; ++e) o[e] = (_Float16)tile[c4 + e][n];
            *(f16x4*)&dst[(long)(n0 + n) * Sc + k0 + c4] = o;
        }
    } else {
        // ---- maskpack ----
        const int idx = (bx - 3584) * 256 + t;
        const uint4 a = ((const uint4*)mask)[idx * 2];
        const uint4 b = ((const uint4*)mask)[idx * 2 + 1];
        unsigned int wsv[8] = {a.x, a.y, a.z, a.w, b.x, b.y, b.z, b.w};
        unsigned int r = 0;
        #pragma unroll
        for (int j = 0; j < 8; ++j) {
            unsigned int nib = (wsv[j] | (wsv[j] >> 7) | (wsv[j] >> 14) | (wsv[j] >> 21)) & 0xFu;
            r |= nib << (4 * j);
        }
        mbits[idx] = r;
    }
}

// ---------------------------------------------------------------------------
// K2: KR GEMM, k-split x2.  KRp[ks][b][n][hd] = sum_{k half} relT * Kt
// ---------------------------------------------------------------------------
__global__ __launch_bounds__(256) void kr_kernel(
    const _Float16* __restrict__ relT, const _Float16* __restrict__ Kt,
    float* __restrict__ KRp)
{
    constexpr int LDK = 72;
    __shared__ _Float16 As[64][LDK];
    __shared__ _Float16 Bs[64][LDK];
    const int z = blockIdx.z;
    const int b = z >> 1, ks = z & 1;
    const int m0 = blockIdx.y * 64;
    const int n0 = blockIdx.x * 64;
    const _Float16* Ap = relT + (long)b * Sc * Sc;
    const _Float16* Bp = Kt + (long)b * Hc * DKc * Sc;
    const int t = threadIdx.x;
    const int lane = t & 63, wave = t >> 6;
    const int wr = wave >> 1, wc = wave & 1;
    const int c = lane & 15, g = lane >> 4;
    const int lrow = t >> 2;
    const int lcol = (t & 3) * 16;
    f32x4 acc[2][2] = {};
    for (int k0 = ks * 1024; k0 < ks * 1024 + 1024; k0 += 64) {
        *(f16x8*)&As[lrow][lcol]     = *(const f16x8*)&Ap[(long)(m0 + lrow) * Sc + k0 + lcol];
        *(f16x8*)&As[lrow][lcol + 8] = *(const f16x8*)&Ap[(long)(m0 + lrow) * Sc + k0 + lcol + 8];
        *(f16x8*)&Bs[lrow][lcol]     = *(const f16x8*)&Bp[(long)(n0 + lrow) * Sc + k0 + lcol];
        *(f16x8*)&Bs[lrow][lcol + 8] = *(const f16x8*)&Bp[(long)(n0 + lrow) * Sc + k0 + lcol + 8];
        __syncthreads();
        #pragma unroll
        for (int kk = 0; kk < 2; ++kk) {
            const int kb = kk * 32 + g * 8;
            f16x8 af[2], bf[2];
            #pragma unroll
            for (int m = 0; m < 2; ++m)
                af[m] = *(const f16x8*)&As[wr * 32 + m * 16 + c][kb];
            #pragma unroll
            for (int n = 0; n < 2; ++n)
                bf[n] = *(const f16x8*)&Bs[wc * 32 + n * 16 + c][kb];
            #pragma unroll
            for (int m = 0; m < 2; ++m)
                #pragma unroll
                for (int n = 0; n < 2; ++n)
                    acc[m][n] = __builtin_amdgcn_mfma_f32_16x16x32_f16(
                        af[m], bf[n], acc[m][n], 0, 0, 0);
        }
        __syncthreads();
    }
    float* outp = KRp + ((long)ks * Bc + b) * Sc * 256;
    #pragma unroll
    for (int m = 0; m < 2; ++m)
        #pragma unroll
        for (int n = 0; n < 2; ++n)
            #pragma unroll
            for (int i = 0; i < 4; ++i) {
                int row = m0 + wr * 32 + m * 16 + g * 4 + i;
                int col = n0 + wc * 32 + n * 16 + c;
                outp[(long)row * 256 + col] = acc[m][n][i];
            }
}

// ---------------------------------------------------------------------------
// K2b: KRT = f16(KRp[0] + KRp[1])
// ---------------------------------------------------------------------------
__global__ __launch_bounds__(256) void krc_kernel(
    const float* __restrict__ KRp, _Float16* __restrict__ KRT)
{
    const long idx = ((long)blockIdx.x * 256 + threadIdx.x) * 4;
    const long half = (long)Bc * Sc * 256;
    f32x4 a = *(const f32x4*)&KRp[idx];
    f32x4 b = *(const f32x4*)&KRp[half + idx];
    f16x4 o;
    #pragma unroll
    for (int i = 0; i < 4; ++i) o[i] = (_Float16)(a[i] + b[i]);
    *(f16x4*)&KRT[idx] = o;
}

// ---------------------------------------------------------------------------
// K3a: esum + PV pass, n-split x4.  grid (32 q-tiles, BH, 4 ns) = 2048.
// Writes partial esum_p[ns][bh][q], UNNORMALIZED accp[ns][bh][q][32].
// ---------------------------------------------------------------------------
__global__ __launch_bounds__(256) void attn_pv_kernel(
    const _Float16* __restrict__ Qb,   // [BH][S][32], pre-scaled
    const _Float16* __restrict__ KRT,  // [B][S][256]
    const _Float16* __restrict__ Vt,   // [BH][32][S]
    const unsigned int* __restrict__ mbits, // [B][S][S/32]
    float* __restrict__ esum_p,        // [4][BH][S]
    float* __restrict__ accp)          // [4][BH][S][32]
{
    constexpr int NT = 128, LDP = 136;
    __shared__ _Float16 p_lds[64][LDP];
    const int bh = blockIdx.y;
    const int ns = blockIdx.z;
    const int b = bh >> 3, h = bh & 7;
    const int q0 = blockIdx.x * 64;
    const int t = threadIdx.x, lane = t & 63, w = t >> 6;
    const int c = lane & 15, g = lane >> 4;
    const int q = q0 + w * 16 + c;
    const f16x8 qf = *(const f16x8*)&Qb[((long)bh * Sc + q) * DKc + g * 8];
    const _Float16* krt = KRT + (long)b * Sc * 256 + h * 32;
    const unsigned int* mbitrow = mbits + ((long)b * Sc + q) * (Sc / 32);
    const f32x4 zero = {};
    f32x4 acc[2] = {};
    float esum = 0.f;

    for (int nt = ns * 4; nt < ns * 4 + 4; ++nt) {
        const int n0 = nt * NT;
        f32x4 s[8];
        #pragma unroll
        for (int nf = 0; nf < 8; ++nf) {
            f16x8 kf = *(const f16x8*)&krt[(long)(n0 + nf * 16 + c) * 256 + g * 8];
            s[nf] = __builtin_amdgcn_mfma_f32_16x16x32_f16(kf, qf, zero, 0, 0, 0);
        }
        const uint4 mq = *(const uint4*)&mbitrow[nt * 4];
        const unsigned int mwv[4] = {mq.x, mq.y, mq.z, mq.w};
        #pragma unroll
        for (int nf = 0; nf < 8; ++nf) {
            const unsigned int bits = mwv[nf >> 1] >> ((nf & 1) * 16 + g * 4);
            f16x4 pv;
            #pragma unroll
            for (int i = 0; i < 4; ++i) {
                float p = ((bits >> i) & 1u) ? 0.f : __expf(s[nf][i]);
                esum += p;
                pv[i] = (_Float16)p;
            }
            *(f16x4*)&p_lds[w * 16 + c][nf * 16 + g * 4] = pv;
        }
        #pragma unroll
        for (int ks = 0; ks < 4; ++ks) {
            f16x8 af = *(const f16x8*)&p_lds[w * 16 + c][ks * 32 + g * 8];
            #pragma unroll
            for (int nb = 0; nb < 2; ++nb) {
                f16x8 vf = *(const f16x8*)&Vt[((long)bh * DKc + nb * 16 + c) * Sc + n0 + ks * 32 + g * 8];
                acc[nb] = __builtin_amdgcn_mfma_f32_16x16x32_f16(af, vf, acc[nb], 0, 0, 0);
            }
        }
    }
    esum += __shfl_xor(esum, 16);
    esum += __shfl_xor(esum, 32);
    if (lane < 16)
        esum_p[((long)ns * BH + bh) * Sc + q0 + w * 16 + lane] = esum;
    #pragma unroll
    for (int nb = 0; nb < 2; ++nb)
        #pragma unroll
        for (int i = 0; i < 4; ++i) {
            const long qrow = q0 + w * 16 + g * 4 + i;
            accp[(((long)ns * BH + bh) * Sc + qrow) * 32 + nb * 16 + c] = acc[nb][i];
        }
}

// ---------------------------------------------------------------------------
// K3b: attn store pass.  Grid (16 n-tiles, 32 q-tiles, 16 bh) = 8192 blocks.
// rinv computed inline from the 4 esum partials (L2-resident).
// ---------------------------------------------------------------------------
__global__ __launch_bounds__(256) void attn_store_kernel(
    const _Float16* __restrict__ Qb,   // [BH][S][32]
    const _Float16* __restrict__ KRT,  // [B][S][256]
    const unsigned int* __restrict__ mbits, // [B][S][S/32]
    const float* __restrict__ esum_p,  // [4][BH][S]
    float* __restrict__ attn_out)      // [BH][S][S]
{
    constexpr int LDA = 132;
    __shared__ float a_lds[4][16][LDA];
    const int nt = blockIdx.x;
    const int q0 = blockIdx.y * 64;
    const int bh = blockIdx.z;
    const int b = bh >> 3, h = bh & 7;
    const int t = threadIdx.x, lane = t & 63, w = t >> 6;
    const int c = lane & 15, g = lane >> 4;
    const int q = q0 + w * 16 + c;
    const int n0 = nt * 128;
    const f16x8 qf = *(const f16x8*)&Qb[((long)bh * Sc + q) * DKc + g * 8];
    const _Float16* krt = KRT + (long)b * Sc * 256 + h * 32;
    const long row = (long)bh * Sc + q;
    const long BHS = (long)BH * Sc;
    const float es = esum_p[row] + esum_p[BHS + row]
                   + esum_p[2 * BHS + row] + esum_p[3 * BHS + row];
    const float rinv = 1.f / es;
    const f32x4 zero = {};

    f32x4 s[8];
    #pragma unroll
    for (int nf = 0; nf < 8; ++nf) {
        f16x8 kf = *(const f16x8*)&krt[(long)(n0 + nf * 16 + c) * 256 + g * 8];
        s[nf] = __builtin_amdgcn_mfma_f32_16x16x32_f16(kf, qf, zero, 0, 0, 0);
    }
    const uint4 mq = *(const uint4*)&mbits[((long)b * Sc + q) * (Sc / 32) + nt * 4];
    const unsigned int mwv[4] = {mq.x, mq.y, mq.z, mq.w};
    #pragma unroll
    for (int nf = 0; nf < 8; ++nf) {
        const unsigned int bits = mwv[nf >> 1] >> ((nf & 1) * 16 + g * 4);
        f32x4 av;
        #pragma unroll
        for (int i = 0; i < 4; ++i)
            av[i] = ((bits >> i) & 1u) ? 0.f : __expf(s[nf][i]) * rinv;
        *(f32x4*)&a_lds[w][c][nf * 16 + g * 4] = av;
    }
    float* aoutw = attn_out + (long)bh * Sc * Sc
                 + (long)(q0 + w * 16 + (lane >> 5)) * Sc + (lane & 31) * 4 + n0;
    #pragma unroll
    for (int r2 = 0; r2 < 8; ++r2) {
        f32x4 v = *(const f32x4*)&a_lds[w][r2 * 2 + (lane >> 5)][(lane & 31) * 4];
        __builtin_nontemporal_store(v, (f32x4*)&aoutw[(long)(r2 * 2) * Sc]);
    }
}

// ---------------------------------------------------------------------------
// K4: out = LayerNorm((accp-combined, normalized) @ Wfc + bfc + query)
// Reads attn partials directly; no attw intermediate.
// ---------------------------------------------------------------------------
__global__ __launch_bounds__(256) void out_kernel(
    const float* __restrict__ accp,    // [4][BH][S][32]
    const float* __restrict__ esum_p,  // [4][BH][S]
    const float* __restrict__ Wfc,
    const float* __restrict__ bfc, const float* __restrict__ query,
    const float* __restrict__ gamma, const float* __restrict__ beta,
    float* __restrict__ out)
{
    __shared__ float xs[4][Dc];
    __shared__ float ys[4][Dc];
    const int r0 = blockIdx.x * 4;
    const int t = threadIdx.x;
    const int h = t >> 5, dk = t & 31;
    const long BHS = (long)BH * Sc;
    #pragma unroll
    for (int i = 0; i < 4; ++i) {
        const long row = r0 + i;                 // b*S + q
        const int b = (int)(row >> 11);
        const int q = (int)(row & 2047);
        const long bhq = ((long)(b * Hc + h)) * Sc + q;
        float es = 0.f, av = 0.f;
        #pragma unroll
        for (int ns = 0; ns < 4; ++ns) {
            es += esum_p[ns * BHS + bhq];
            av += accp[(ns * BHS + bhq) * 32 + dk];
        }
        xs[i][t] = av / es;
    }
    __syncthreads();
    float acc[4] = {0.f, 0.f, 0.f, 0.f};
    for (int d = 0; d < Dc; ++d) {
        float wv = Wfc[d * Dc + t];
        #pragma unroll
        for (int i = 0; i < 4; ++i) acc[i] = fmaf(xs[i][d], wv, acc[i]);
    }
    const float bias = bfc[t];
    #pragma unroll
    for (int i = 0; i < 4; ++i)
        ys[i][t] = acc[i] + bias + query[(long)(r0 + i) * Dc + t];
    __syncthreads();
    const int w = t >> 6, lane = t & 63;
    float x0 = ys[w][lane], x1 = ys[w][lane + 64];
    float x2 = ys[w][lane + 128], x3 = ys[w][lane + 192];
    float sum = x0 + x1 + x2 + x3;
    float sq = x0 * x0 + x1 * x1 + x2 * x2 + x3 * x3;
    for (int off = 32; off; off >>= 1) {
        sum += __shfl_down(sum, off);
        sq  += __shfl_down(sq, off);
    }
    sum = __shfl(sum, 0);
    sq  = __shfl(sq, 0);
    const float mu = sum * (1.f / 256.f);
    const float var = sq * (1.f / 256.f) - mu * mu;
    const float rstd = rsqrtf(var + 1e-5f);
    float* orow = out + (long)(r0 + w) * Dc;
    orow[lane]       = (x0 - mu) * rstd * gamma[lane]       + beta[lane];
    orow[lane + 64]  = (x1 - mu) * rstd * gamma[lane + 64]  + beta[lane + 64];
    orow[lane + 128] = (x2 - mu) * rstd * gamma[lane + 128] + beta[lane + 128];
    orow[lane + 192] = (x3 - mu) * rstd * gamma[lane + 192] + beta[lane + 192];
}

// ---------------------------------------------------------------------------
extern "C" void kernel_launch(void* const* d_in, const int* in_sizes, int n_in,
                              void* d_out, int out_size, void* d_ws, size_t ws_size,
                              hipStream_t stream)
{
    const float* query   = (const float*)d_in[0];
    const float* key_    = (const float*)d_in[1];
    const float* value   = (const float*)d_in[2];
    const unsigned int* mask = (const unsigned int*)d_in[3];
    const float* relation = (const float*)d_in[4];
    const float* Wq  = (const float*)d_in[5];
    const float* Wk  = (const float*)d_in[6];
    const float* Wv  = (const float*)d_in[7];
    const float* Wfc = (const float*)d_in[8];
    const float* bfc = (const float*)d_in[9];
    const float* gamma = (const float*)d_in[10];
    const float* beta  = (const float*)d_in[11];

    float* out_ln   = (float*)d_out;
    float* out_attn = (float*)d_out + (size_t)Bc * Sc * Dc;

    char* ws = (char*)d_ws;
    _Float16* Qb   = (_Float16*)(ws + 0);          //  2 MB [BH][S][32]
    _Float16* Kt   = (_Float16*)(ws + 2097152);    //  2 MB [B][H][32][S]
    _Float16* Vt   = (_Float16*)(ws + 4194304);    //  2 MB [BH][32][S]
    _Float16* relT = (_Float16*)(ws + 6291456);    // 16.8 MB [B][S][S] (n,k)
    _Float16* KRT  = (_Float16*)(ws + 23068672);   //  2 MB [B][S][256]
    unsigned int* mbits = (unsigned int*)(ws + 29360128); // 1 MB
    float*    KRp   = (float*)  (ws + 30539776);   // 8.4 MB [2][B][S][256]
    float*    esum_p= (float*)  (ws + 38928384);   // 512 KB [4][BH][S]
    float*    accp  = (float*)  (ws + 39452672);   // 16.8 MB [4][BH][S][32]

    prep_kernel<<<dim3(4096), 256, 0, stream>>>(
        query, key_, value, Wq, Wk, Wv, relation, mask,
        Qb, Kt, Vt, relT, mbits);
    kr_kernel<<<dim3(4, Sc / 64, Bc * 2), 256, 0, stream>>>(relT, Kt, KRp);
    krc_kernel<<<dim3(Bc * Sc * 256 / 4 / 256), 256, 0, stream>>>(KRp, KRT);
    attn_pv_kernel<<<dim3(Sc / 64, BH, 4), 256, 0, stream>>>(
        Qb, KRT, Vt, mbits, esum_p, accp);
    attn_store_kernel<<<dim3(Sc / 128, Sc / 64, BH), 256, 0, stream>>>(
        Qb, KRT, mbits, esum_p, out_attn);
    out_kernel<<<dim3(Bc * Sc / 4), 256, 0, stream>>>(accp, esum_p, Wfc, bfc,
                                                      query, gamma, beta, out_ln);
}